// Round 2
// baseline (3198.385 us; speedup 1.0000x reference)
//
#include <hip/hip_runtime.h>

typedef unsigned short ushort_t;
typedef unsigned int uint_t;
typedef __attribute__((ext_vector_type(8))) short short8;
typedef __attribute__((ext_vector_type(4))) float f32x4;

#define LDS_AS __attribute__((address_space(3)))
#define GLB_AS __attribute__((address_space(1)))

__device__ __forceinline__ float bf2f(ushort_t h) {
    uint_t u = ((uint_t)h) << 16;
    return __builtin_bit_cast(float, u);
}
__device__ __forceinline__ ushort_t f2bf(float f) {
    uint_t u = __builtin_bit_cast(uint_t, f);
    u += 0x7fffu + ((u >> 16) & 1u);
    return (ushort_t)(u >> 16);
}

// ---------------------------------------------------------------------------
// fp32 -> bf16 convert, 8 elements/thread, vectorized.
// ---------------------------------------------------------------------------
__global__ __launch_bounds__(256) void cvt_kernel(const float* __restrict__ src,
                                                  ushort_t* __restrict__ dst) {
    size_t i = ((size_t)blockIdx.x * 256 + threadIdx.x) * 8;
    f32x4 a = *(const f32x4*)(src + i);
    f32x4 b = *(const f32x4*)(src + i + 4);
    short8 o;
#pragma unroll
    for (int j = 0; j < 4; ++j) o[j] = (short)f2bf(a[j]);
#pragma unroll
    for (int j = 0; j < 4; ++j) o[4 + j] = (short)f2bf(b[j]);
    *(short8*)(dst + i) = o;
}

// ---------------------------------------------------------------------------
// GEMM: C[M,N] = A[M,K] * W[N,K]^T, bf16 in, fp32 accum, bf16 or f32 out.
// 128x128 block tile, BK=32, 4 waves (2x2), each wave 64x64 = 4x4 MFMA tiles.
// global_load_lds width=16 staging (m97 structure).
// ---------------------------------------------------------------------------
template <bool OUT_F32>
__global__ __launch_bounds__(256) void gemm_bt(const ushort_t* __restrict__ A,
                                               const ushort_t* __restrict__ W,
                                               void* __restrict__ Cv,
                                               int M, int N, int K) {
    __shared__ ushort_t As[128 * 32];
    __shared__ ushort_t Bs[128 * 32];
    const int tid = threadIdx.x;
    const int lane = tid & 63;
    const int w = tid >> 6;
    const int wr = (w >> 1) * 64;
    const int wc = (w & 1) * 64;
    const int row0 = blockIdx.y * 128;
    const int col0 = blockIdx.x * 128;
    const int l15 = lane & 15;
    const int l4 = lane >> 4;

    f32x4 acc[4][4];
#pragma unroll
    for (int i = 0; i < 4; ++i)
#pragma unroll
        for (int j = 0; j < 4; ++j) acc[i][j] = (f32x4)0.0f;

    for (int k0 = 0; k0 < K; k0 += 32) {
        __syncthreads();
        // Stage A-tile (128x32) and W-tile (128x32): 512 chunks of 16B each,
        // chunk c -> row c>>2, cols (c&3)*8..+7.  LDS dst per wave is
        // uniform-base + lane*16 (hardware requirement).
#pragma unroll
        for (int i = 0; i < 2; ++i) {
            int c = i * 256 + tid;
            int r = c >> 2;
            int cc = (c & 3) * 8;
            __builtin_amdgcn_global_load_lds(
                (const GLB_AS void*)(A + (size_t)(row0 + r) * K + k0 + cc),
                (LDS_AS void*)(&As[c * 8]), 16, 0, 0);
            __builtin_amdgcn_global_load_lds(
                (const GLB_AS void*)(W + (size_t)(col0 + r) * K + k0 + cc),
                (LDS_AS void*)(&Bs[c * 8]), 16, 0, 0);
        }
        __syncthreads();  // drains vmcnt for global_load_lds

        short8 aF[4], bF[4];
#pragma unroll
        for (int mt = 0; mt < 4; ++mt)
            aF[mt] = *(const short8*)&As[(wr + mt * 16 + l15) * 32 + l4 * 8];
#pragma unroll
        for (int nt = 0; nt < 4; ++nt)
            bF[nt] = *(const short8*)&Bs[(wc + nt * 16 + l15) * 32 + l4 * 8];
#pragma unroll
        for (int mt = 0; mt < 4; ++mt)
#pragma unroll
            for (int nt = 0; nt < 4; ++nt)
                acc[mt][nt] = __builtin_amdgcn_mfma_f32_16x16x32_bf16(
                    aF[mt], bF[nt], acc[mt][nt], 0, 0, 0);
    }

    // C/D layout: col = lane&15, row = (lane>>4)*4 + reg  (m89/m91 verified)
#pragma unroll
    for (int mt = 0; mt < 4; ++mt)
#pragma unroll
        for (int nt = 0; nt < 4; ++nt)
#pragma unroll
            for (int r = 0; r < 4; ++r) {
                int row = row0 + wr + mt * 16 + l4 * 4 + r;
                int col = col0 + wc + nt * 16 + l15;
                if (OUT_F32)
                    ((float*)Cv)[(size_t)row * N + col] = acc[mt][nt][r];
                else
                    ((ushort_t*)Cv)[(size_t)row * N + col] = f2bf(acc[mt][nt][r]);
            }
}

// ---------------------------------------------------------------------------
// RoPE (in-place, bf16). One thread per (row, head, pair j). rotate-half:
// out[j] = x[j]*cos - x[j+64]*sin ; out[j+64] = x[j+64]*cos + x[j]*sin
// ang = s * 10000^(-j/64), s = row % 2048.
// ---------------------------------------------------------------------------
__global__ __launch_bounds__(256) void rope_kernel(ushort_t* __restrict__ X,
                                                   int lognh) {
    int idx = blockIdx.x * 256 + threadIdx.x;
    int j = idx & 63;
    int t = idx >> 6;
    int h = t & ((1 << lognh) - 1);
    int r = t >> lognh;
    int s = r & 2047;
    int stride = 128 << lognh;
    size_t ofs = (size_t)r * stride + h * 128 + j;
    // inv_freq = 10000^(-j/64) = 2^(-j * log2(10000)/64)
    float inv = exp2f(-0.20762050593046014f * (float)j);
    float ang = (float)s * inv;
    float c = cosf(ang);
    float sn = sinf(ang);
    float x1 = bf2f(X[ofs]);
    float x2 = bf2f(X[ofs + 64]);
    X[ofs] = f2bf(x1 * c - x2 * sn);
    X[ofs + 64] = f2bf(x2 * c + x1 * sn);
}

// ---------------------------------------------------------------------------
// Causal GQA flash attention (vector-ALU version).
// One block per (b, h, 64-query tile). 256 threads = 16x16 (ty, tx).
// Thread computes scores for queries qy=ty*4+i, keys kx=tx*4+jj (4x4),
// and owns O[qy][tx*8 .. +7]. Online softmax, row reductions via shfl_xor
// across the 16 tx lanes (wave-local: wave w holds ty = 4w..4w+3).
// ---------------------------------------------------------------------------
__global__ __launch_bounds__(256) void attn_kernel(const ushort_t* __restrict__ Q,
                                                   const ushort_t* __restrict__ K,
                                                   const ushort_t* __restrict__ V,
                                                   ushort_t* __restrict__ Cx) {
    __shared__ ushort_t Qs[64 * 130];   // +2 ushort pad -> stride 65 uints
    __shared__ ushort_t Ks[64 * 130];
    __shared__ ushort_t Vs[64 * 130];
    __shared__ ushort_t Ps[64 * 66];    // P tile, bf16

    const int tid = threadIdx.x;
    const int tx = tid & 15;
    const int ty = tid >> 4;

    const int blk = blockIdx.x;
    const int qt = blk & 31;
    const int h = (blk >> 5) & 31;
    const int b = blk >> 10;
    const int kvh = h >> 2;   // GQA: 32 q-heads -> 8 kv-heads

    // Load Q tile (64 x 128 bf16) into LDS
#pragma unroll
    for (int i = 0; i < 4; ++i) {
        int c = i * 256 + tid;
        int r = c >> 4;
        int cc = c & 15;
        size_t gofs = (size_t)(b * 2048 + qt * 64 + r) * 4096 + h * 128 + cc * 8;
        const uint_t* gp = (const uint_t*)(Q + gofs);
        uint_t* lp = (uint_t*)&Qs[r * 130 + cc * 8];
        lp[0] = gp[0]; lp[1] = gp[1]; lp[2] = gp[2]; lp[3] = gp[3];
    }

    float m_i[4], l_i[4], O[4][8];
#pragma unroll
    for (int i = 0; i < 4; ++i) {
        m_i[i] = -1.0e30f;
        l_i[i] = 0.0f;
#pragma unroll
        for (int d = 0; d < 8; ++d) O[i][d] = 0.0f;
    }

    const float scale = 0.08838834764831845f;  // 128^-0.5
    const uint_t* Qu = (const uint_t*)Qs;
    const uint_t* Ku = (const uint_t*)Ks;

    for (int kt = 0; kt <= qt; ++kt) {
        __syncthreads();  // previous PV reads of Ks/Vs done (also covers Qs load)
#pragma unroll
        for (int i = 0; i < 4; ++i) {
            int c = i * 256 + tid;
            int r = c >> 4;
            int cc = c & 15;
            size_t gofs = (size_t)(b * 2048 + kt * 64 + r) * 1024 + kvh * 128 + cc * 8;
            const uint_t* gk = (const uint_t*)(K + gofs);
            uint_t* lk = (uint_t*)&Ks[r * 130 + cc * 8];
            lk[0] = gk[0]; lk[1] = gk[1]; lk[2] = gk[2]; lk[3] = gk[3];
            const uint_t* gv = (const uint_t*)(V + gofs);
            uint_t* lv = (uint_t*)&Vs[r * 130 + cc * 8];
            lv[0] = gv[0]; lv[1] = gv[1]; lv[2] = gv[2]; lv[3] = gv[3];
        }
        __syncthreads();

        // ---- scores: s[4][4] over d (bf16x2 per uint) ----
        float s[4][4];
#pragma unroll
        for (int i = 0; i < 4; ++i)
#pragma unroll
            for (int jj = 0; jj < 4; ++jj) s[i][jj] = 0.0f;

#pragma unroll 8
        for (int d2 = 0; d2 < 64; ++d2) {
            uint_t qu[4], ku[4];
#pragma unroll
            for (int i = 0; i < 4; ++i) qu[i] = Qu[(ty * 4 + i) * 65 + d2];
#pragma unroll
            for (int jj = 0; jj < 4; ++jj) ku[jj] = Ku[(tx * 4 + jj) * 65 + d2];
#pragma unroll
            for (int i = 0; i < 4; ++i) {
                float qlo = __builtin_bit_cast(float, qu[i] << 16);
                float qhi = __builtin_bit_cast(float, qu[i] & 0xffff0000u);
#pragma unroll
                for (int jj = 0; jj < 4; ++jj) {
                    float klo = __builtin_bit_cast(float, ku[jj] << 16);
                    float khi = __builtin_bit_cast(float, ku[jj] & 0xffff0000u);
                    s[i][jj] += qlo * klo + qhi * khi;
                }
            }
        }

        // ---- mask + online softmax update ----
#pragma unroll
        for (int i = 0; i < 4; ++i) {
            int qy = ty * 4 + i;
#pragma unroll
            for (int jj = 0; jj < 4; ++jj) {
                int kx = tx * 4 + jj;
                float sv = s[i][jj] * scale;
                if (kt == qt && kx > qy) sv = -1.0e30f;
                s[i][jj] = sv;
            }
            float rm = fmaxf(fmaxf(s[i][0], s[i][1]), fmaxf(s[i][2], s[i][3]));
#pragma unroll
            for (int d = 1; d <= 8; d <<= 1) rm = fmaxf(rm, __shfl_xor(rm, d, 64));
            float newm = fmaxf(m_i[i], rm);
            float alpha = __expf(m_i[i] - newm);
            m_i[i] = newm;
            float rs = 0.0f;
#pragma unroll
            for (int jj = 0; jj < 4; ++jj) {
                float p = __expf(s[i][jj] - newm);
                s[i][jj] = p;
                rs += p;
            }
#pragma unroll
            for (int d = 1; d <= 8; d <<= 1) rs += __shfl_xor(rs, d, 64);
            l_i[i] = l_i[i] * alpha + rs;
#pragma unroll
            for (int d = 0; d < 8; ++d) O[i][d] *= alpha;
#pragma unroll
            for (int jj = 0; jj < 4; ++jj)
                Ps[qy * 66 + tx * 4 + jj] = f2bf(s[i][jj]);
        }
        __syncthreads();

        // ---- O += P * V ----
#pragma unroll 4
        for (int k = 0; k < 64; ++k) {
            float pv[4];
#pragma unroll
            for (int i = 0; i < 4; ++i) pv[i] = bf2f(Ps[(ty * 4 + i) * 66 + k]);
            const uint_t* vk = (const uint_t*)&Vs[k * 130 + tx * 8];
            float vf[8];
#pragma unroll
            for (int u = 0; u < 4; ++u) {
                uint_t vv = vk[u];
                vf[2 * u] = __builtin_bit_cast(float, vv << 16);
                vf[2 * u + 1] = __builtin_bit_cast(float, vv & 0xffff0000u);
            }
#pragma unroll
            for (int i = 0; i < 4; ++i)
#pragma unroll
                for (int d = 0; d < 8; ++d) O[i][d] += pv[i] * vf[d];
        }
    }

    // epilogue: O /= l, write ctx (bf16)
#pragma unroll
    for (int i = 0; i < 4; ++i) {
        float rl = 1.0f / l_i[i];
        int qy = ty * 4 + i;
        size_t gofs = (size_t)(b * 2048 + qt * 64 + qy) * 4096 + h * 128 + tx * 8;
        ushort_t tmp[8];
#pragma unroll
        for (int d = 0; d < 8; ++d) tmp[d] = f2bf(O[i][d] * rl);
        uint_t* gp = (uint_t*)(Cx + gofs);
        const uint_t* tp = (const uint_t*)tmp;
        gp[0] = tp[0]; gp[1] = tp[1]; gp[2] = tp[2]; gp[3] = tp[3];
    }
}

// ---------------------------------------------------------------------------
extern "C" void kernel_launch(void* const* d_in, const int* in_sizes, int n_in,
                              void* d_out, int out_size, void* d_ws, size_t ws_size,
                              hipStream_t stream) {
    const float* q  = (const float*)d_in[0];
    const float* k  = (const float*)d_in[1];
    const float* v  = (const float*)d_in[2];
    const float* Wq = (const float*)d_in[3];
    const float* Wk = (const float*)d_in[4];
    const float* Wv = (const float*)d_in[5];
    const float* Wd = (const float*)d_in[6];
    float* out = (float*)d_out;

    char* ws = (char*)d_ws;
    // 144 MB total workspace
    ushort_t* Abf = (ushort_t*)(ws);                       // 16.7M bf16 = 32MB (activation)
    ushort_t* Wbf = (ushort_t*)(ws + (size_t)33554432);    // 16.7M bf16 = 32MB (weight)
    ushort_t* Qb  = (ushort_t*)(ws + (size_t)67108864);    // 4096x4096 bf16 = 32MB
    ushort_t* Kb  = (ushort_t*)(ws + (size_t)100663296);   // 4096x1024 bf16 =  8MB
    ushort_t* Vb  = (ushort_t*)(ws + (size_t)109051904);   // 4096x1024 bf16 =  8MB
    ushort_t* Cx  = (ushort_t*)(ws + (size_t)117440512);   // 4096x4096 bf16 = 32MB

    dim3 blk(256);
    // Q projection
    hipLaunchKernelGGL(cvt_kernel, dim3(8192), blk, 0, stream, q, Abf);
    hipLaunchKernelGGL(cvt_kernel, dim3(8192), blk, 0, stream, Wq, Wbf);
    hipLaunchKernelGGL((gemm_bt<false>), dim3(32, 32), blk, 0, stream, Abf, Wbf, (void*)Qb, 4096, 4096, 4096);
    // K projection
    hipLaunchKernelGGL(cvt_kernel, dim3(8192), blk, 0, stream, k, Abf);
    hipLaunchKernelGGL(cvt_kernel, dim3(2048), blk, 0, stream, Wk, Wbf);
    hipLaunchKernelGGL((gemm_bt<false>), dim3(8, 32), blk, 0, stream, Abf, Wbf, (void*)Kb, 4096, 1024, 4096);
    // V projection
    hipLaunchKernelGGL(cvt_kernel, dim3(8192), blk, 0, stream, v, Abf);
    hipLaunchKernelGGL(cvt_kernel, dim3(2048), blk, 0, stream, Wv, Wbf);
    hipLaunchKernelGGL((gemm_bt<false>), dim3(8, 32), blk, 0, stream, Abf, Wbf, (void*)Vb, 4096, 1024, 4096);
    // RoPE
    hipLaunchKernelGGL(rope_kernel, dim3(32768), blk, 0, stream, Qb, 5);  // 32 heads
    hipLaunchKernelGGL(rope_kernel, dim3(8192),  blk, 0, stream, Kb, 3);  //  8 heads
    // Attention
    hipLaunchKernelGGL(attn_kernel, dim3(2048), blk, 0, stream, Qb, Kb, Vb, Cx);
    // Output projection (fp32 out)
    hipLaunchKernelGGL(cvt_kernel, dim3(8192), blk, 0, stream, Wd, Wbf);
    hipLaunchKernelGGL((gemm_bt<true>), dim3(32, 32), blk, 0, stream, Cx, Wbf, (void*)out, 4096, 4096, 4096);
}

// Round 3
// 1561.428 us; speedup vs baseline: 2.0484x; 2.0484x over previous
//
#include <hip/hip_runtime.h>

typedef unsigned short ushort_t;
typedef unsigned int uint_t;
typedef __attribute__((ext_vector_type(8))) short short8;
typedef __attribute__((ext_vector_type(4))) short s16x4;
typedef __attribute__((ext_vector_type(4))) float f32x4;

#define LDS_AS __attribute__((address_space(3)))
#define GLB_AS __attribute__((address_space(1)))

__device__ __forceinline__ float bf2f(ushort_t h) {
    uint_t u = ((uint_t)h) << 16;
    return __builtin_bit_cast(float, u);
}
__device__ __forceinline__ ushort_t f2bf(float f) {
    uint_t u = __builtin_bit_cast(uint_t, f);
    u += 0x7fffu + ((u >> 16) & 1u);
    return (ushort_t)(u >> 16);
}

// ---------------------------------------------------------------------------
// fp32 -> bf16 convert, 8 elements/thread, vectorized.
// ---------------------------------------------------------------------------
__global__ __launch_bounds__(256) void cvt_kernel(const float* __restrict__ src,
                                                  ushort_t* __restrict__ dst) {
    size_t i = ((size_t)blockIdx.x * 256 + threadIdx.x) * 8;
    f32x4 a = *(const f32x4*)(src + i);
    f32x4 b = *(const f32x4*)(src + i + 4);
    short8 o;
#pragma unroll
    for (int j = 0; j < 4; ++j) o[j] = (short)f2bf(a[j]);
#pragma unroll
    for (int j = 0; j < 4; ++j) o[4 + j] = (short)f2bf(b[j]);
    *(short8*)(dst + i) = o;
}

// ---------------------------------------------------------------------------
// GEMM: C[M,N] = A[M,K] * W[N,K]^T, bf16 in, fp32 accum, bf16 or f32 out.
// 128x128 block tile, BK=32, 4 waves (2x2), each wave 64x64 = 4x4 MFMA tiles.
// global_load_lds width=16 staging (m97 structure).
// ---------------------------------------------------------------------------
template <bool OUT_F32>
__global__ __launch_bounds__(256) void gemm_bt(const ushort_t* __restrict__ A,
                                               const ushort_t* __restrict__ W,
                                               void* __restrict__ Cv,
                                               int M, int N, int K) {
    __shared__ ushort_t As[128 * 32];
    __shared__ ushort_t Bs[128 * 32];
    const int tid = threadIdx.x;
    const int lane = tid & 63;
    const int w = tid >> 6;
    const int wr = (w >> 1) * 64;
    const int wc = (w & 1) * 64;
    const int row0 = blockIdx.y * 128;
    const int col0 = blockIdx.x * 128;
    const int l15 = lane & 15;
    const int l4 = lane >> 4;

    f32x4 acc[4][4];
#pragma unroll
    for (int i = 0; i < 4; ++i)
#pragma unroll
        for (int j = 0; j < 4; ++j) acc[i][j] = (f32x4)0.0f;

    for (int k0 = 0; k0 < K; k0 += 32) {
        __syncthreads();
#pragma unroll
        for (int i = 0; i < 2; ++i) {
            int c = i * 256 + tid;
            int r = c >> 2;
            int cc = (c & 3) * 8;
            __builtin_amdgcn_global_load_lds(
                (const GLB_AS void*)(A + (size_t)(row0 + r) * K + k0 + cc),
                (LDS_AS void*)(&As[c * 8]), 16, 0, 0);
            __builtin_amdgcn_global_load_lds(
                (const GLB_AS void*)(W + (size_t)(col0 + r) * K + k0 + cc),
                (LDS_AS void*)(&Bs[c * 8]), 16, 0, 0);
        }
        __syncthreads();

        short8 aF[4], bF[4];
#pragma unroll
        for (int mt = 0; mt < 4; ++mt)
            aF[mt] = *(const short8*)&As[(wr + mt * 16 + l15) * 32 + l4 * 8];
#pragma unroll
        for (int nt = 0; nt < 4; ++nt)
            bF[nt] = *(const short8*)&Bs[(wc + nt * 16 + l15) * 32 + l4 * 8];
#pragma unroll
        for (int mt = 0; mt < 4; ++mt)
#pragma unroll
            for (int nt = 0; nt < 4; ++nt)
                acc[mt][nt] = __builtin_amdgcn_mfma_f32_16x16x32_bf16(
                    aF[mt], bF[nt], acc[mt][nt], 0, 0, 0);
    }

    // C/D layout: col = lane&15, row = (lane>>4)*4 + reg
#pragma unroll
    for (int mt = 0; mt < 4; ++mt)
#pragma unroll
        for (int nt = 0; nt < 4; ++nt)
#pragma unroll
            for (int r = 0; r < 4; ++r) {
                int row = row0 + wr + mt * 16 + l4 * 4 + r;
                int col = col0 + wc + nt * 16 + l15;
                if (OUT_F32)
                    ((float*)Cv)[(size_t)row * N + col] = acc[mt][nt][r];
                else
                    ((ushort_t*)Cv)[(size_t)row * N + col] = f2bf(acc[mt][nt][r]);
            }
}

// ---------------------------------------------------------------------------
// RoPE (in-place, bf16). ang = s * 10000^(-j/64), s = row % 2048.
// ---------------------------------------------------------------------------
__global__ __launch_bounds__(256) void rope_kernel(ushort_t* __restrict__ X,
                                                   int lognh) {
    int idx = blockIdx.x * 256 + threadIdx.x;
    int j = idx & 63;
    int t = idx >> 6;
    int h = t & ((1 << lognh) - 1);
    int r = t >> lognh;
    int s = r & 2047;
    int stride = 128 << lognh;
    size_t ofs = (size_t)r * stride + h * 128 + j;
    float inv = exp2f(-0.20762050593046014f * (float)j);
    float ang = (float)s * inv;
    float c = cosf(ang);
    float sn = sinf(ang);
    float x1 = bf2f(X[ofs]);
    float x2 = bf2f(X[ofs + 64]);
    X[ofs] = f2bf(x1 * c - x2 * sn);
    X[ofs + 64] = f2bf(x2 * c + x1 * sn);
}

// ---------------------------------------------------------------------------
// MFMA flash attention (causal, GQA 4:1).
// Block = (b, h, 64-query tile); 4 waves x 16 q-rows. BK=64 keys/iter.
// Q frags in registers (loaded once). K frags loaded from global per iter
// (L1/L2-cached, shared across the 4 waves + 4 GQA heads).
// V staged transposed into LDS (Vt[128][72]). P round-trips through LDS as
// fp32 (Ps[64][68]) to convert MFMA C-layout -> A-layout.
// MFMA layouts (verified via gemm_bt): A/B lane holds [m|n = lane&15]
// [k=(lane>>4)*8+j]; C/D col=lane&15, row=(lane>>4)*4+reg.
// ---------------------------------------------------------------------------
__global__ __launch_bounds__(256, 3) void attn_kernel(const ushort_t* __restrict__ Q,
                                                      const ushort_t* __restrict__ K,
                                                      const ushort_t* __restrict__ V,
                                                      ushort_t* __restrict__ Cx) {
    __shared__ ushort_t Vt[128 * 72];  // V^T: Vt[d][key], stride 72 (pad)
    __shared__ float Ps[64 * 68];      // P fp32: Ps[q][key], stride 68 (pad)

    const int tid = threadIdx.x;
    const int l = tid & 63;
    const int w = tid >> 6;
    const int l15 = l & 15;
    const int l4 = l >> 4;

    const int blk = blockIdx.x;
    const int qt = blk & 31;
    const int h = (blk >> 5) & 31;
    const int b = blk >> 10;
    const int kvh = h >> 2;

    const size_t qrow0 = (size_t)(b * 2048 + qt * 64 + w * 16);

    // ---- Q fragments: 16 q-rows x 128 d, once per block ----
    short8 qf[4];
    {
        const ushort_t* qp = Q + (qrow0 + l15) * 4096 + h * 128 + l4 * 8;
#pragma unroll
        for (int kt = 0; kt < 4; ++kt) qf[kt] = *(const short8*)(qp + kt * 32);
    }

    f32x4 O[8];
#pragma unroll
    for (int dt = 0; dt < 8; ++dt) O[dt] = (f32x4)0.0f;
    float m_i[4], l_i[4];
#pragma unroll
    for (int r = 0; r < 4; ++r) { m_i[r] = -1.0e30f; l_i[r] = 0.0f; }

    const float scale = 0.08838834764831845f;  // 128^-0.5

    // V staging assignment: thread -> 4 adjacent keys x 8 adjacent d
    const int sk0 = (tid & 15) * 4;
    const int sd0 = (tid >> 4) * 8;

    for (int kti = 0; kti <= qt; ++kti) {
        __syncthreads();  // prev-iter PV reads of Vt done

        // ---- stage V transposed: Vt[d][key] = V[key][d] ----
        {
            const ushort_t* vp = V + (size_t)(b * 2048 + kti * 64 + sk0) * 1024 +
                                 kvh * 128 + sd0;
            short8 vr[4];
#pragma unroll
            for (int i = 0; i < 4; ++i) vr[i] = *(const short8*)(vp + i * 1024);
#pragma unroll
            for (int j = 0; j < 8; ++j) {
                s16x4 pk;
                pk[0] = vr[0][j]; pk[1] = vr[1][j];
                pk[2] = vr[2][j]; pk[3] = vr[3][j];
                *(s16x4*)&Vt[(sd0 + j) * 72 + sk0] = pk;
            }
        }

        // ---- QK^T: S[16q x 64k] per wave ----
        const ushort_t* kbase = K + (size_t)(b * 2048 + kti * 64) * 1024 + kvh * 128;
        f32x4 S[4];
#pragma unroll
        for (int ct = 0; ct < 4; ++ct) {
            S[ct] = (f32x4)0.0f;
            const ushort_t* kp = kbase + (size_t)(ct * 16 + l15) * 1024 + l4 * 8;
#pragma unroll
            for (int kt = 0; kt < 4; ++kt) {
                short8 kf = *(const short8*)(kp + kt * 32);
                S[ct] = __builtin_amdgcn_mfma_f32_16x16x32_bf16(qf[kt], kf, S[ct], 0, 0, 0);
            }
        }

        // ---- online softmax (per C-layout row r: q = w*16 + l4*4 + r) ----
        const int diag = (kti == qt);
#pragma unroll
        for (int r = 0; r < 4; ++r) {
            int qy = w * 16 + l4 * 4 + r;
            float sv[4];
#pragma unroll
            for (int ct = 0; ct < 4; ++ct) {
                float x = S[ct][r] * scale;
                if (diag && (ct * 16 + l15) > qy) x = -1.0e30f;
                sv[ct] = x;
            }
            float rm = fmaxf(fmaxf(sv[0], sv[1]), fmaxf(sv[2], sv[3]));
#pragma unroll
            for (int d = 1; d <= 8; d <<= 1) rm = fmaxf(rm, __shfl_xor(rm, d, 64));
            float nm = fmaxf(m_i[r], rm);
            float al = __expf(m_i[r] - nm);
            m_i[r] = nm;
            float rs = 0.0f;
#pragma unroll
            for (int ct = 0; ct < 4; ++ct) {
                float p = __expf(sv[ct] - nm);
                Ps[(size_t)qy * 68 + ct * 16 + l15] = p;
                rs += p;
            }
#pragma unroll
            for (int d = 1; d <= 8; d <<= 1) rs += __shfl_xor(rs, d, 64);
            l_i[r] = l_i[r] * al + rs;
#pragma unroll
            for (int dt = 0; dt < 8; ++dt) O[dt][r] *= al;
        }

        __syncthreads();  // Vt writes (+ Ps, same-wave) visible

        // ---- O += P * V  (A = P from Ps, B = Vt) ----
#pragma unroll
        for (int kpt = 0; kpt < 2; ++kpt) {
            f32x4 pa = *(const f32x4*)&Ps[(size_t)(w * 16 + l15) * 68 + kpt * 32 + l4 * 8];
            f32x4 pb = *(const f32x4*)&Ps[(size_t)(w * 16 + l15) * 68 + kpt * 32 + l4 * 8 + 4];
            short8 pf;
#pragma unroll
            for (int j = 0; j < 4; ++j) pf[j] = (short)f2bf(pa[j]);
#pragma unroll
            for (int j = 0; j < 4; ++j) pf[4 + j] = (short)f2bf(pb[j]);
#pragma unroll
            for (int dt = 0; dt < 8; ++dt) {
                short8 vf = *(const short8*)&Vt[(size_t)(dt * 16 + l15) * 72 + kpt * 32 + l4 * 8];
                O[dt] = __builtin_amdgcn_mfma_f32_16x16x32_bf16(pf, vf, O[dt], 0, 0, 0);
            }
        }
    }

    // ---- epilogue: O /= l, write ctx (bf16) ----
    float rl[4];
#pragma unroll
    for (int r = 0; r < 4; ++r) rl[r] = 1.0f / l_i[r];
#pragma unroll
    for (int dt = 0; dt < 8; ++dt)
#pragma unroll
        for (int r = 0; r < 4; ++r) {
            size_t gofs = (qrow0 + l4 * 4 + r) * 4096 + h * 128 + dt * 16 + l15;
            Cx[gofs] = f2bf(O[dt][r] * rl[r]);
        }
}

// ---------------------------------------------------------------------------
extern "C" void kernel_launch(void* const* d_in, const int* in_sizes, int n_in,
                              void* d_out, int out_size, void* d_ws, size_t ws_size,
                              hipStream_t stream) {
    const float* q  = (const float*)d_in[0];
    const float* k  = (const float*)d_in[1];
    const float* v  = (const float*)d_in[2];
    const float* Wq = (const float*)d_in[3];
    const float* Wk = (const float*)d_in[4];
    const float* Wv = (const float*)d_in[5];
    const float* Wd = (const float*)d_in[6];
    float* out = (float*)d_out;

    char* ws = (char*)d_ws;
    ushort_t* Abf = (ushort_t*)(ws);                       // 32MB (activation bf16)
    ushort_t* Wbf = (ushort_t*)(ws + (size_t)33554432);    // 32MB (weight bf16)
    ushort_t* Qb  = (ushort_t*)(ws + (size_t)67108864);    // 4096x4096 bf16 = 32MB
    ushort_t* Kb  = (ushort_t*)(ws + (size_t)100663296);   // 4096x1024 bf16 =  8MB
    ushort_t* Vb  = (ushort_t*)(ws + (size_t)109051904);   // 4096x1024 bf16 =  8MB
    ushort_t* Cx  = (ushort_t*)(ws + (size_t)117440512);   // 4096x4096 bf16 = 32MB

    dim3 blk(256);
    // Q projection
    hipLaunchKernelGGL(cvt_kernel, dim3(8192), blk, 0, stream, q, Abf);
    hipLaunchKernelGGL(cvt_kernel, dim3(8192), blk, 0, stream, Wq, Wbf);
    hipLaunchKernelGGL((gemm_bt<false>), dim3(32, 32), blk, 0, stream, Abf, Wbf, (void*)Qb, 4096, 4096, 4096);
    // K projection
    hipLaunchKernelGGL(cvt_kernel, dim3(8192), blk, 0, stream, k, Abf);
    hipLaunchKernelGGL(cvt_kernel, dim3(2048), blk, 0, stream, Wk, Wbf);
    hipLaunchKernelGGL((gemm_bt<false>), dim3(8, 32), blk, 0, stream, Abf, Wbf, (void*)Kb, 4096, 1024, 4096);
    // V projection
    hipLaunchKernelGGL(cvt_kernel, dim3(8192), blk, 0, stream, v, Abf);
    hipLaunchKernelGGL(cvt_kernel, dim3(2048), blk, 0, stream, Wv, Wbf);
    hipLaunchKernelGGL((gemm_bt<false>), dim3(8, 32), blk, 0, stream, Abf, Wbf, (void*)Vb, 4096, 1024, 4096);
    // RoPE
    hipLaunchKernelGGL(rope_kernel, dim3(32768), blk, 0, stream, Qb, 5);  // 32 heads
    hipLaunchKernelGGL(rope_kernel, dim3(8192),  blk, 0, stream, Kb, 3);  //  8 heads
    // Attention (MFMA)
    hipLaunchKernelGGL(attn_kernel, dim3(2048), blk, 0, stream, Qb, Kb, Vb, Cx);
    // Output projection (fp32 out)
    hipLaunchKernelGGL(cvt_kernel, dim3(8192), blk, 0, stream, Wd, Wbf);
    hipLaunchKernelGGL((gemm_bt<true>), dim3(32, 32), blk, 0, stream, Cx, Wbf, (void*)out, 4096, 4096, 4096);
}